// Round 6
// baseline (278.282 us; speedup 1.0000x reference)
//
#include <hip/hip_runtime.h>
#include <cstdint>
#include <cstddef>

typedef unsigned short u16;
typedef __bf16 bf16x8 __attribute__((ext_vector_type(8)));
typedef float f32x4 __attribute__((ext_vector_type(4)));
typedef unsigned int u32x4 __attribute__((ext_vector_type(4)));
typedef unsigned int u32x2 __attribute__((ext_vector_type(2)));
typedef u16 u16x4 __attribute__((ext_vector_type(4)));

typedef __attribute__((address_space(3))) void lds_void;
typedef __attribute__((address_space(1))) void glb_void;

constexpr float CEXP = 92.33248261689366f;   // 64 * log2(e): folded into Q

// ---------------- workspace layout (u16 element offsets) ----------------
constexpr size_t XSZ = 4096ull * 1024ull;   // one [4096,1024] bf16 array
constexpr size_t WSZ = 1024ull * 1024ull;   // one [1024,1024] bf16 array
constexpr size_t OFF_XQH = 0;
constexpr size_t OFF_XQL = OFF_XQH + XSZ;
constexpr size_t OFF_XKH = OFF_XQL + XSZ;
constexpr size_t OFF_XKL = OFF_XKH + XSZ;
constexpr size_t OFF_XVH = OFF_XKL + XSZ;
constexpr size_t OFF_XVL = OFF_XVH + XSZ;   // UNUSED (kept for layout stability)
constexpr size_t OFF_WQH = OFF_XVL + XSZ;
constexpr size_t OFF_WQL = OFF_WQH + WSZ;
constexpr size_t OFF_WKH = OFF_WQL + WSZ;
constexpr size_t OFF_WKL = OFF_WKH + WSZ;
constexpr size_t OFF_WVH = OFF_WKL + WSZ;
constexpr size_t OFF_WVL = OFF_WVH + WSZ;   // UNUSED
constexpr size_t OFF_QH  = OFF_WVL + WSZ;   // [B,H,S,64]  (pre-scaled by CEXP)
constexpr size_t OFF_QL  = OFF_QH + XSZ;
constexpr size_t OFF_KH  = OFF_QL + XSZ;
constexpr size_t OFF_KL  = OFF_KH + XSZ;
constexpr size_t OFF_VH  = OFF_KL + XSZ;    // UNUSED (V-GEMM writes VT directly)
constexpr size_t OFF_VT  = OFF_VH + XSZ;    // [B,H,64,S]

// ---------------- helpers ----------------
__device__ __forceinline__ u16 f2b(float f) {           // fp32 -> bf16 RNE
  unsigned u = __builtin_bit_cast(unsigned, f);
  return (u16)((u + 0x7FFFu + ((u >> 16) & 1u)) >> 16);
}
__device__ __forceinline__ float b2f(u16 h) {
  return __builtin_bit_cast(float, ((unsigned)h) << 16);
}
__device__ __forceinline__ bf16x8 ld8(const u16* p) {   // 16B frag load
  return __builtin_bit_cast(bf16x8, *(const u32x4*)p);
}
__device__ __forceinline__ unsigned pk2(float a, float b) {  // pack 2 bf16 (RNE)
#if __has_builtin(__builtin_amdgcn_cvt_pk_bf16_f32)
  auto v = __builtin_amdgcn_cvt_pk_bf16_f32(a, b);
  return __builtin_bit_cast(unsigned, v);
#else
  return (unsigned)f2b(a) | ((unsigned)f2b(b) << 16);
#endif
}
__device__ __forceinline__ float ex2(float x) {         // raw v_exp_f32
#if __has_builtin(__builtin_amdgcn_exp2f)
  return __builtin_amdgcn_exp2f(x);
#else
  return exp2f(x);
#endif
}
__device__ __forceinline__ void glds16(const u16* g, u16* l) { // 16B global->LDS
  __builtin_amdgcn_global_load_lds((const glb_void*)g, (lds_void*)l, 16, 0, 0);
}
// swizzled LDS offset for a [rows][32 u16] tile: chunk = 8 u16 (16B)
__device__ __forceinline__ int swz32(int row, int cg) {
  return row * 32 + ((cg ^ ((row >> 1) & 3)) * 8);
}
// swizzled LDS offset for a [rows][64 u16] tile: chunk = 8 u16 (16B)
__device__ __forceinline__ int swz64(int row, int cg) {
  return row * 64 + ((cg ^ (row & 7)) * 8);
}

// ---------------- fused converts: x (hi/lo) + W^T (hi/lo) ----------------
__global__ __launch_bounds__(256) void convert_all(const float* __restrict__ q,
                                                   const float* __restrict__ k,
                                                   const float* __restrict__ v,
                                                   const float* __restrict__ Wq,
                                                   const float* __restrict__ Wk,
                                                   const float* __restrict__ Wv,
                                                   u16* __restrict__ ws) {
  __shared__ float tile[32][33];
  int id = blockIdx.x;
  int t = threadIdx.x;
  if (id < 12288) {                       // ---- x path: 4096 blocks per z ----
    int z = id >> 12, blk = id & 4095;
    const float* in = (z == 0) ? q : (z == 1) ? k : v;
    u16* hi = ws + ((z == 0) ? OFF_XQH : (z == 1) ? OFF_XKH : OFF_XVH);
    u16* lo = ws + ((z == 0) ? OFF_XQL : (z == 1) ? OFF_XKL : OFF_XVL);
    size_t i = ((size_t)blk * 256u + t) * 4u;
    float4 vv = *(const float4*)(in + i);
    float a[4] = {vv.x, vv.y, vv.z, vv.w};
    u16x4 hv, lv;
#pragma unroll
    for (int j = 0; j < 4; ++j) {
      u16 hb = f2b(a[j]);
      hv[j] = hb;
      lv[j] = f2b(a[j] - b2f(hb));
    }
    *(u16x4*)(hi + i) = hv;
    if (z != 2) *(u16x4*)(lo + i) = lv;
  } else {                                // ---- W path: 1024 blocks per z ----
    int r0 = id - 12288;
    int z = r0 >> 10, rem = r0 & 1023;
    const float* W = (z == 0) ? Wq : (z == 1) ? Wk : Wv;
    u16* hiT = ws + ((z == 0) ? OFF_WQH : (z == 1) ? OFF_WKH : OFF_WVH);
    u16* loT = ws + ((z == 0) ? OFF_WQL : (z == 1) ? OFF_WKL : OFF_WVL);
    int n0 = (rem & 31) * 32, k0 = (rem >> 5) * 32;
    int r = t >> 3, c0 = (t & 7) * 4;
    float4 vv = *(const float4*)(W + (size_t)(k0 + r) * 1024 + n0 + c0);
    tile[r][c0] = vv.x; tile[r][c0 + 1] = vv.y; tile[r][c0 + 2] = vv.z; tile[r][c0 + 3] = vv.w;
    __syncthreads();
    u16x4 hv, lv;
#pragma unroll
    for (int j = 0; j < 4; ++j) {
      float x = tile[c0 + j][r];          // = W[k0+c0+j][n0+r]
      u16 hb = f2b(x);
      hv[j] = hb;
      lv[j] = f2b(x - b2f(hb));
    }
    size_t o = (size_t)(n0 + r) * 1024 + k0 + c0;
    *(u16x4*)(hiT + o) = hv;
    if (z != 2) *(u16x4*)(loT + o) = lv;
  }
}

// ---------------- QKV projection GEMM, 64x128 tile, 4 waves ------------------
__global__ __launch_bounds__(256, 4) void gemm_qkv(u16* __restrict__ ws) {
  __shared__ u16 sA[2][64 * 32];      // hi/lo A: 4 KB each
  __shared__ u16 sB[2][128 * 32];     // hi/lo B: 8 KB each; reused as C buffer
  u16* cbuf = &sB[0][0];              // 64x128 u16 = 16 KB epilogue view

  int id = blockIdx.x;
  int xcd = id & 7, seq = id >> 3;          // assume round-robin dispatch
  int pair = (seq >> 3) * 8 + xcd;          // 0..191, z-balanced per XCD
  int tile_n = seq & 7;
  int z = pair >> 6;                        // pair / 64
  int tile_m = pair & 63;

  const u16 *Ah, *Al, *Bh, *Bl; u16 *Oh, *Ol; bool split;
  if (z == 0)      { Ah = ws + OFF_XQH; Al = ws + OFF_XQL; Bh = ws + OFF_WQH; Bl = ws + OFF_WQL; Oh = ws + OFF_QH; Ol = ws + OFF_QL; split = true; }
  else if (z == 1) { Ah = ws + OFF_XKH; Al = ws + OFF_XKL; Bh = ws + OFF_WKH; Bl = ws + OFF_WKL; Oh = ws + OFF_KH; Ol = ws + OFF_KL; split = true; }
  else             { Ah = ws + OFF_XVH; Al = nullptr;      Bh = ws + OFF_WVH; Bl = nullptr;      Oh = ws + OFF_VT; Ol = nullptr;    split = false; }
  float oscale = (z == 0) ? CEXP : 1.0f;
  int m0 = tile_m * 64, n0 = tile_n * 128;
  int t = threadIdx.x, lane = t & 63, wave = t >> 6;
  int quad = lane >> 4, l15 = lane & 15;
  int wm = (wave >> 1) * 32, wn = (wave & 1) * 64;
  int rl = lane >> 2, cgl = lane & 3;       // staging: 16 rows x 4 chunks/issue
  f32x4 acc[2][4] = {};

  int rowA = wave * 16 + rl;
  size_t gA = (size_t)(m0 + rowA) * 1024 + (cgl ^ ((rowA >> 1) & 3)) * 8;
  int lbA = wave * 512;
  size_t gB[2]; int lbB[2];
#pragma unroll
  for (int i = 0; i < 2; ++i) {
    int rowB = wave * 32 + i * 16 + rl;
    gB[i] = (size_t)(n0 + rowB) * 1024 + (cgl ^ ((rowB >> 1) & 3)) * 8;
    lbB[i] = wave * 1024 + i * 512;
  }

  for (int kb = 0; kb < 32; ++kb) {
    int k0 = kb * 32;
    __syncthreads();
    glds16(Ah + gA + k0, &sA[0][lbA]);
    if (split) glds16(Al + gA + k0, &sA[1][lbA]);
#pragma unroll
    for (int i = 0; i < 2; ++i) {
      glds16(Bh + gB[i] + k0, &sB[0][lbB[i]]);
      if (split) glds16(Bl + gB[i] + k0, &sB[1][lbB[i]]);
    }
    __syncthreads();
    bf16x8 afh[2], afl[2], bfh[4], bfl[4];
#pragma unroll
    for (int mt = 0; mt < 2; ++mt) {
      int ra = wm + mt * 16 + l15;
      afh[mt] = ld8(&sA[0][swz32(ra, quad)]);
      if (split) afl[mt] = ld8(&sA[1][swz32(ra, quad)]);
    }
#pragma unroll
    for (int nt = 0; nt < 4; ++nt) {
      int rb = wn + nt * 16 + l15;
      bfh[nt] = ld8(&sB[0][swz32(rb, quad)]);
      if (split) bfl[nt] = ld8(&sB[1][swz32(rb, quad)]);
    }
#pragma unroll
    for (int mt = 0; mt < 2; ++mt)
#pragma unroll
      for (int nt = 0; nt < 4; ++nt) {
        acc[mt][nt] = __builtin_amdgcn_mfma_f32_16x16x32_bf16(afh[mt], bfh[nt], acc[mt][nt], 0, 0, 0);
        if (split) {
          acc[mt][nt] = __builtin_amdgcn_mfma_f32_16x16x32_bf16(afl[mt], bfh[nt], acc[mt][nt], 0, 0, 0);
          acc[mt][nt] = __builtin_amdgcn_mfma_f32_16x16x32_bf16(afh[mt], bfl[nt], acc[mt][nt], 0, 0, 0);
        }
      }
  }
  auto epi_round = [&](u16* dst, bool lo_round) {
#pragma unroll
    for (int mt = 0; mt < 2; ++mt)
#pragma unroll
      for (int nt = 0; nt < 4; ++nt)
#pragma unroll
        for (int r = 0; r < 4; ++r) {
          int row = wm + mt * 16 + quad * 4 + r;
          int col = wn + nt * 16 + l15;
          float v = acc[mt][nt][r] * oscale;
          u16 hb = f2b(v);
          u16 val = lo_round ? f2b(v - b2f(hb)) : hb;
          cbuf[row * 128 + (((col >> 3) ^ (row & 15)) * 8) + (col & 7)] = val;
        }
    __syncthreads();
    int row = t >> 2, seg = t & 3;
    int gm = m0 + row, bb = gm >> 11, s = gm & 2047;
    int hh = (n0 >> 6) + (seg >> 1), d0 = (seg & 1) * 32;
    u16* gp = dst + ((size_t)(bb * 16 + hh) * 2048 + s) * 64 + d0;
#pragma unroll
    for (int i = 0; i < 4; ++i) {
      int phys = (seg * 4 + i) ^ (row & 15);
      *(u32x4*)(gp + i * 8) = *(const u32x4*)(&cbuf[row * 128 + phys * 8]);
    }
  };
  __syncthreads();                 // staging reads done; cbuf free
  if (split) {
    epi_round(Oh, false);
    __syncthreads();
    epi_round(Ol, true);
  } else {
#pragma unroll
    for (int mt = 0; mt < 2; ++mt)
#pragma unroll
      for (int nt = 0; nt < 4; ++nt)
#pragma unroll
        for (int r = 0; r < 4; ++r) {
          int row = wm + mt * 16 + quad * 4 + r;       // seq within tile
          int col = wn + nt * 16 + l15;                // dim within 128 (2 heads)
          cbuf[row * 128 + (((col >> 3) ^ (row & 15)) * 8) + (col & 7)] =
              f2b(acc[mt][nt][r]);
        }
    __syncthreads();
    int col = t >> 1, sh = t & 1;
    int hg = (n0 + col) >> 6, d = (n0 + col) & 63;
    int bb = m0 >> 11, s0 = m0 & 2047;
    u16 vals[32];
#pragma unroll
    for (int i = 0; i < 32; ++i) {
      int row = sh * 32 + i;
      vals[i] = cbuf[row * 128 + (((col >> 3) ^ (row & 15)) * 8) + (col & 7)];
    }
    u16* gp = Oh + ((size_t)((bb * 16 + hg) * 64 + d)) * 2048 + s0 + sh * 32;
#pragma unroll
    for (int i = 0; i < 4; ++i)
      *(u32x4*)(gp + i * 8) = *(const u32x4*)(&vals[i * 8]);
  }
}

// ---------------- flash attention: 64 Q-rows/block, 64-key tiles -------------
// R13 (resubmit after infra failure; identities re-audited):
// (a) APPROX-FIRST QK: 8 kh*qh MFMAs -> approx max tree -> skip-test at
//     mi-32 (hi*hi approx error ~<4 exp2-units; implies the exact -28 test).
//     Dead tiles (~25%) skip the 16 correction MFMAs, exp/pack, and all PV.
// (b) IN-REGISTER P redistribution: 16 __shfl + 8 selects replace the
//     ds_write/lgkmcnt(0)-drain/ds_read round-trip (lp deleted: LDS 32->24 KB).
//     key = 16*(2ks+(quad>>1)) + 4*((quad&1)*2+(w>>1)) + 2*(w&1) identity.
// (c) SWAPPED PV (o^T = mfma(V-frag A, P B)): O/lsum/mi/alpha all in the
//     lane=qrow domain -> no alpha broadcasts; contiguous f32x4 epilogue.
__global__ __launch_bounds__(256, 4) void attn(const u16* __restrict__ ws,
                                               float* __restrict__ out) {
  __shared__ u16 lkh[64 * 64];
  __shared__ u16 lkl[64 * 64];
  __shared__ u16 lvt[64 * 64];
  const u16* Qh = ws + OFF_QH; const u16* Ql = ws + OFF_QL;
  const u16* Kh = ws + OFF_KH; const u16* Kl = ws + OFF_KL;
  const u16* Vt = ws + OFF_VT;
  // ---- XCD-grouped decode: xcd owns heads [xcd*4, xcd*4+4) ----
  int id = blockIdx.x;
  int xcd = id & 7, slot = id >> 3;            // slot 0..127
  int hh = xcd * 4 + (slot >> 5);              // 0..31  (b*16+h)
  int q0 = (slot & 31) * 64;
  int b = hh >> 4, h = hh & 15;
  int t = threadIdx.x, lane = t & 63, wave = t >> 6;
  int quad = lane >> 4, l15 = lane & 15;
  size_t hb = (size_t)hh * (2048 * 64);
  bf16x8 onesf;                                  // ones A-frag for row-sum MFMA
#pragma unroll
  for (int j = 0; j < 8; ++j) onesf[j] = __builtin_bit_cast(__bf16, (u16)0x3F80);
  // Q fragments (B operand: lane holds qrow=lane&15, 8 consecutive d)
  int qrow = q0 + wave * 16 + l15;
  bf16x8 qfh[2], qfl[2];
#pragma unroll
  for (int ks = 0; ks < 2; ++ks) {
    size_t qo = hb + (size_t)qrow * 64 + ks * 32 + quad * 8;
    qfh[ks] = ld8(Qh + qo);
    qfl[ks] = ld8(Ql + qo);
  }
  float mi = -1e30f;                 // running max for qrow=l15
  f32x4 lsum = {};                   // row-sum accumulator (all regs equal)
  f32x4 o[4] = {};                   // o^T: col=l15=qrow, row=d
  int rl = lane >> 3, cgl = lane & 7;            // staging: 8 rows x 8 chunks/issue

  size_t aK[2], aV[2]; int lb[2];
#pragma unroll
  for (int i = 0; i < 2; ++i) {
    int row = wave * 16 + i * 8 + rl;            // tile-local row 0..63
    int cgg = cgl ^ (row & 7);
    aK[i] = hb + (size_t)row * 64 + cgg * 8;     // + kt*4096 in-loop
    aV[i] = hb + (size_t)row * 2048 + cgg * 8;   // + kt*64  in-loop
    lb[i] = (wave * 16 + i * 8) * 64;
  }
  int soF[2][4];
#pragma unroll
  for (int ks = 0; ks < 2; ++ks)
#pragma unroll
    for (int nt = 0; nt < 4; ++nt)
      soF[ks][nt] = swz64(nt * 16 + l15, ks * 4 + quad);

  // ---- prologue: stage tile 0 via global_load_lds ----
#pragma unroll
  for (int i = 0; i < 2; ++i) {
    glds16(Kh + aK[i], &lkh[lb[i]]);
    glds16(Kl + aK[i], &lkl[lb[i]]);
    glds16(Vt + aV[i], &lvt[lb[i]]);
  }
  __syncthreads();

  for (int kt = 0; kt < 32; ++kt) {
    // ---- T14 issue-early: prefetch tile kt+1 into registers ----
    u32x4 pk_[2], pl_[2], pv_[2];
    if (kt < 31) {
#pragma unroll
      for (int i = 0; i < 2; ++i) {
        pk_[i] = *(const u32x4*)(Kh + aK[i] + (kt + 1) * 4096);
        pl_[i] = *(const u32x4*)(Kl + aK[i] + (kt + 1) * 4096);
        pv_[i] = *(const u32x4*)(Vt + aV[i] + (kt + 1) * 64);
      }
    }
    // ---- approx QK^T: hi*hi only (8 MFMAs) ----
    f32x4 sc[4] = {};
    __builtin_amdgcn_s_setprio(1);
#pragma unroll
    for (int nt = 0; nt < 4; ++nt)
#pragma unroll
      for (int ks = 0; ks < 2; ++ks) {
        bf16x8 kh_ = ld8(&lkh[soF[ks][nt]]);
        sc[nt] = __builtin_amdgcn_mfma_f32_16x16x32_bf16(kh_, qfh[ks], sc[nt], 0, 0, 0);
      }
    __builtin_amdgcn_s_setprio(0);
    {
      float t0 = fmaxf(fmaxf(sc[0][0], sc[0][1]), sc[0][2]);
      float t1 = fmaxf(fmaxf(sc[0][3], sc[1][0]), sc[1][1]);
      float t2 = fmaxf(fmaxf(sc[1][2], sc[1][3]), sc[2][0]);
      float t3 = fmaxf(fmaxf(sc[2][1], sc[2][2]), sc[2][3]);
      float t4 = fmaxf(fmaxf(sc[3][0], sc[3][1]), sc[3][2]);
      float mxa = fmaxf(fmaxf(fmaxf(t0, t1), fmaxf(t2, t3)), fmaxf(t4, sc[3][3]));
      mxa = fmaxf(mxa, __shfl_xor(mxa, 16));
      mxa = fmaxf(mxa, __shfl_xor(mxa, 32));
      if (__ballot(mxa > mi - 32.0f)) {
        // ---- corrections: kl*qh + kh*ql (16 MFMAs) ----
        __builtin_amdgcn_s_setprio(1);
#pragma unroll
        for (int nt = 0; nt < 4; ++nt)
#pragma unroll
          for (int ks = 0; ks < 2; ++ks) {
            bf16x8 kh_ = ld8(&lkh[soF[ks][nt]]);
            bf16x8 kl_ = ld8(&lkl[soF[ks][nt]]);
            sc[nt] = __builtin_amdgcn_mfma_f32_16x16x32_bf16(kl_, qfh[ks], sc[nt], 0, 0, 0);
            sc[nt] = __builtin_amdgcn_mfma_f32_16x16x32_bf16(kh_, qfl[ks], sc[nt], 0, 0, 0);
          }
        __builtin_amdgcn_s_setprio(0);
        // ---- exact max tree ----
        float e0 = fmaxf(fmaxf(sc[0][0], sc[0][1]), sc[0][2]);
        float e1 = fmaxf(fmaxf(sc[0][3], sc[1][0]), sc[1][1]);
        float e2 = fmaxf(fmaxf(sc[1][2], sc[1][3]), sc[2][0]);
        float e3 = fmaxf(fmaxf(sc[2][1], sc[2][2]), sc[2][3]);
        float e4 = fmaxf(fmaxf(sc[3][0], sc[3][1]), sc[3][2]);
        float mx = fmaxf(fmaxf(fmaxf(e0, e1), fmaxf(e2, e3)), fmaxf(e4, sc[3][3]));
        mx = fmaxf(mx, __shfl_xor(mx, 16));
        mx = fmaxf(mx, __shfl_xor(mx, 32));
        float mi_old = mi;
        unsigned long long live = __ballot(mx > mi_old - 28.0f);
        float mn = fmaxf(mi_old, mx);
        if (live) {
          unsigned long long grew = __ballot(mx > mi_old);
          // ---- P = exp2(sc - mn) packed: u[nt][pair] = keys nt*16+quad*4+2p ----
          unsigned u[4][2];
#pragma unroll
          for (int nt = 0; nt < 4; ++nt) {
            u[nt][0] = pk2(ex2(sc[nt][0] - mn), ex2(sc[nt][1] - mn));
            u[nt][1] = pk2(ex2(sc[nt][2] - mn), ex2(sc[nt][3] - mn));
          }
          if (grew) {
            float a = ex2(mi_old - mn);        // per-lane (qrow=l15) alpha
#pragma unroll
            for (int r = 0; r < 4; ++r) {
              lsum[r] *= a;
              o[0][r] *= a; o[1][r] *= a; o[2][r] *= a; o[3][r] *= a;
            }
          }
          mi = mn;
          // ---- in-register redistribution to B-operand layout:
          // pa[ks] word w = keys 32ks+8*quad+2w from lane srcq*16+l15,
          // srcq=(quad&1)*2+(w>>1), src word u[2ks+(quad>>1)][w&1].
          bf16x8 pa[2];
#pragma unroll
          for (int ks = 0; ks < 2; ++ks) {
            u32x4 w4;
#pragma unroll
            for (int w = 0; w < 4; ++w) {
              int srcl = ((quad & 1) * 2 + (w >> 1)) * 16 + l15;
              unsigned s0 = (unsigned)__shfl((int)u[ks * 2 + 0][w & 1], srcl);
              unsigned s1 = (unsigned)__shfl((int)u[ks * 2 + 1][w & 1], srcl);
              w4[w] = (quad >> 1) ? s1 : s0;
            }
            pa[ks] = __builtin_bit_cast(bf16x8, w4);
          }
          // ---- swapped PV: o^T += V-frag (A) x P (B); lsum via ones-A ----
          __builtin_amdgcn_s_setprio(1);
          lsum = __builtin_amdgcn_mfma_f32_16x16x32_bf16(onesf, pa[0], lsum, 0, 0, 0);
          lsum = __builtin_amdgcn_mfma_f32_16x16x32_bf16(onesf, pa[1], lsum, 0, 0, 0);
#pragma unroll
          for (int nt = 0; nt < 4; ++nt)
#pragma unroll
            for (int ks = 0; ks < 2; ++ks) {
              bf16x8 bv = ld8(&lvt[soF[ks][nt]]);
              o[nt] = __builtin_amdgcn_mfma_f32_16x16x32_bf16(bv, pa[ks], o[nt], 0, 0, 0);
            }
          __builtin_amdgcn_s_setprio(0);
        }
      }
    }
    // ---- write-late: all waves done reading tile kt; commit tile kt+1 ----
    __syncthreads();
    if (kt < 31) {
#pragma unroll
      for (int i = 0; i < 2; ++i) {
        *(u32x4*)(&lkh[lb[i] + lane * 8]) = pk_[i];
        *(u32x4*)(&lkl[lb[i] + lane * 8]) = pl_[i];
        *(u32x4*)(&lvt[lb[i] + lane * 8]) = pv_[i];
      }
    }
    __syncthreads();
  }
  // epilogue: o^T -> out[b, qrow, h*64 + d], contiguous f32x4 per (nt,quad)
  float inv = 1.0f / lsum[0];
  float* op = out + (size_t)(b * 2048 + q0 + wave * 16 + l15) * 1024 + h * 64;
#pragma unroll
  for (int nt = 0; nt < 4; ++nt) {
    f32x4 w;
#pragma unroll
    for (int r = 0; r < 4; ++r) w[r] = o[nt][r] * inv;
    *(f32x4*)(op + nt * 16 + quad * 4) = w;
  }
}

extern "C" void kernel_launch(void* const* d_in, const int* in_sizes, int n_in,
                              void* d_out, int out_size, void* d_ws, size_t ws_size,
                              hipStream_t stream) {
  const float* q  = (const float*)d_in[0];
  const float* k  = (const float*)d_in[1];
  const float* v  = (const float*)d_in[2];
  const float* Wq = (const float*)d_in[3];
  const float* Wk = (const float*)d_in[4];
  const float* Wv = (const float*)d_in[5];
  u16* ws = (u16*)d_ws;
  float* out = (float*)d_out;

  convert_all<<<15360, 256, 0, stream>>>(q, k, v, Wq, Wk, Wv, ws);
  gemm_qkv<<<1536, 256, 0, stream>>>(ws);
  attn<<<1024, 256, 0, stream>>>(ws, out);
}

// Round 7
// 274.639 us; speedup vs baseline: 1.0133x; 1.0133x over previous
//
#include <hip/hip_runtime.h>
#include <cstdint>
#include <cstddef>

typedef unsigned short u16;
typedef __bf16 bf16x8 __attribute__((ext_vector_type(8)));
typedef float f32x4 __attribute__((ext_vector_type(4)));
typedef unsigned int u32x4 __attribute__((ext_vector_type(4)));
typedef unsigned int u32x2 __attribute__((ext_vector_type(2)));
typedef u16 u16x4 __attribute__((ext_vector_type(4)));

typedef __attribute__((address_space(3))) void lds_void;
typedef __attribute__((address_space(1))) void glb_void;

constexpr float CEXP = 92.33248261689366f;   // 64 * log2(e): folded into Q

// ---------------- workspace layout (u16 element offsets) ----------------
constexpr size_t XSZ = 4096ull * 1024ull;   // one [4096,1024] bf16 array
constexpr size_t WSZ = 1024ull * 1024ull;   // one [1024,1024] bf16 array
constexpr size_t OFF_XQH = 0;
constexpr size_t OFF_XQL = OFF_XQH + XSZ;
constexpr size_t OFF_XKH = OFF_XQL + XSZ;
constexpr size_t OFF_XKL = OFF_XKH + XSZ;
constexpr size_t OFF_XVH = OFF_XKL + XSZ;
constexpr size_t OFF_XVL = OFF_XVH + XSZ;   // UNUSED (kept for layout stability)
constexpr size_t OFF_WQH = OFF_XVL + XSZ;
constexpr size_t OFF_WQL = OFF_WQH + WSZ;
constexpr size_t OFF_WKH = OFF_WQL + WSZ;
constexpr size_t OFF_WKL = OFF_WKH + WSZ;
constexpr size_t OFF_WVH = OFF_WKL + WSZ;
constexpr size_t OFF_WVL = OFF_WVH + WSZ;   // UNUSED
constexpr size_t OFF_QH  = OFF_WVL + WSZ;   // [B,H,S,64]  (pre-scaled by CEXP)
constexpr size_t OFF_QL  = OFF_QH + XSZ;
constexpr size_t OFF_KH  = OFF_QL + XSZ;
constexpr size_t OFF_KL  = OFF_KH + XSZ;
constexpr size_t OFF_VH  = OFF_KL + XSZ;    // UNUSED (V-GEMM writes VT directly)
constexpr size_t OFF_VT  = OFF_VH + XSZ;    // [B,H,64,S]

// ---------------- helpers ----------------
__device__ __forceinline__ u16 f2b(float f) {           // fp32 -> bf16 RNE
  unsigned u = __builtin_bit_cast(unsigned, f);
  return (u16)((u + 0x7FFFu + ((u >> 16) & 1u)) >> 16);
}
__device__ __forceinline__ float b2f(u16 h) {
  return __builtin_bit_cast(float, ((unsigned)h) << 16);
}
__device__ __forceinline__ bf16x8 ld8(const u16* p) {   // 16B frag load
  return __builtin_bit_cast(bf16x8, *(const u32x4*)p);
}
__device__ __forceinline__ unsigned pk2(float a, float b) {  // pack 2 bf16 (RNE)
#if __has_builtin(__builtin_amdgcn_cvt_pk_bf16_f32)
  auto v = __builtin_amdgcn_cvt_pk_bf16_f32(a, b);
  return __builtin_bit_cast(unsigned, v);
#else
  return (unsigned)f2b(a) | ((unsigned)f2b(b) << 16);
#endif
}
__device__ __forceinline__ float ex2(float x) {         // raw v_exp_f32
#if __has_builtin(__builtin_amdgcn_exp2f)
  return __builtin_amdgcn_exp2f(x);
#else
  return exp2f(x);
#endif
}
__device__ __forceinline__ void glds16(const u16* g, u16* l) { // 16B global->LDS
  __builtin_amdgcn_global_load_lds((const glb_void*)g, (lds_void*)l, 16, 0, 0);
}
// swizzled LDS offset for a [rows][32 u16] tile: chunk = 8 u16 (16B)
__device__ __forceinline__ int swz32(int row, int cg) {
  return row * 32 + ((cg ^ ((row >> 1) & 3)) * 8);
}
// swizzled LDS offset for a [rows][64 u16] tile: chunk = 8 u16 (16B)
__device__ __forceinline__ int swz64(int row, int cg) {
  return row * 64 + ((cg ^ (row & 7)) * 8);
}

// ---------------- fused converts: x (hi/lo) + W^T (hi/lo) ----------------
__global__ __launch_bounds__(256) void convert_all(const float* __restrict__ q,
                                                   const float* __restrict__ k,
                                                   const float* __restrict__ v,
                                                   const float* __restrict__ Wq,
                                                   const float* __restrict__ Wk,
                                                   const float* __restrict__ Wv,
                                                   u16* __restrict__ ws) {
  __shared__ float tile[32][33];
  int id = blockIdx.x;
  int t = threadIdx.x;
  if (id < 12288) {                       // ---- x path: 4096 blocks per z ----
    int z = id >> 12, blk = id & 4095;
    const float* in = (z == 0) ? q : (z == 1) ? k : v;
    u16* hi = ws + ((z == 0) ? OFF_XQH : (z == 1) ? OFF_XKH : OFF_XVH);
    u16* lo = ws + ((z == 0) ? OFF_XQL : (z == 1) ? OFF_XKL : OFF_XVL);
    size_t i = ((size_t)blk * 256u + t) * 4u;
    float4 vv = *(const float4*)(in + i);
    float a[4] = {vv.x, vv.y, vv.z, vv.w};
    u16x4 hv, lv;
#pragma unroll
    for (int j = 0; j < 4; ++j) {
      u16 hb = f2b(a[j]);
      hv[j] = hb;
      lv[j] = f2b(a[j] - b2f(hb));
    }
    *(u16x4*)(hi + i) = hv;
    if (z != 2) *(u16x4*)(lo + i) = lv;
  } else {                                // ---- W path: 1024 blocks per z ----
    int r0 = id - 12288;
    int z = r0 >> 10, rem = r0 & 1023;
    const float* W = (z == 0) ? Wq : (z == 1) ? Wk : Wv;
    u16* hiT = ws + ((z == 0) ? OFF_WQH : (z == 1) ? OFF_WKH : OFF_WVH);
    u16* loT = ws + ((z == 0) ? OFF_WQL : (z == 1) ? OFF_WKL : OFF_WVL);
    int n0 = (rem & 31) * 32, k0 = (rem >> 5) * 32;
    int r = t >> 3, c0 = (t & 7) * 4;
    float4 vv = *(const float4*)(W + (size_t)(k0 + r) * 1024 + n0 + c0);
    tile[r][c0] = vv.x; tile[r][c0 + 1] = vv.y; tile[r][c0 + 2] = vv.z; tile[r][c0 + 3] = vv.w;
    __syncthreads();
    u16x4 hv, lv;
#pragma unroll
    for (int j = 0; j < 4; ++j) {
      float x = tile[c0 + j][r];          // = W[k0+c0+j][n0+r]
      u16 hb = f2b(x);
      hv[j] = hb;
      lv[j] = f2b(x - b2f(hb));
    }
    size_t o = (size_t)(n0 + r) * 1024 + k0 + c0;
    *(u16x4*)(hiT + o) = hv;
    if (z != 2) *(u16x4*)(loT + o) = lv;
  }
}

// ---------------- QKV projection GEMM, 128x128 tile, 4 waves -----------------
// R14: tile 64x128 -> 128x128 (m93 ladder lever: FLOP/staging-byte 64 -> 96).
// 768 blocks (256 tiles per z), XCD-balanced: pair = (seq>>3)*8 + xcd gives
// each XCD 4 tile-rows per z and keeps all 8 n-tiles of a tile-row on ONE XCD
// (A-row fetched once; W re-reads via L3). Per wave: 64x64 output, acc 4x4.
// Same glds16 + pre-swizzled-global staging; epilogues extended to 128 rows.
__global__ __launch_bounds__(256, 3) void gemm_qkv(u16* __restrict__ ws) {
  __shared__ u16 smem[16384];          // 32 KB: staging arrays / cbuf view
  u16* sAh = smem;                     // [128*32] each (8 KB)
  u16* sAl = smem + 4096;
  u16* sBh = smem + 8192;
  u16* sBl = smem + 12288;
  u16* cbuf = smem;                    // 128x128 u16 epilogue view (32 KB)

  int id = blockIdx.x;
  int xcd = id & 7, seq = id >> 3;          // seq 0..95
  int pair = (seq >> 3) * 8 + xcd;          // 0..95, z-balanced per XCD
  int tile_n = seq & 7;
  int z = pair >> 5;                        // 0..2
  int tile_m = pair & 31;

  const u16 *Ah, *Al, *Bh, *Bl; u16 *Oh, *Ol; bool split;
  if (z == 0)      { Ah = ws + OFF_XQH; Al = ws + OFF_XQL; Bh = ws + OFF_WQH; Bl = ws + OFF_WQL; Oh = ws + OFF_QH; Ol = ws + OFF_QL; split = true; }
  else if (z == 1) { Ah = ws + OFF_XKH; Al = ws + OFF_XKL; Bh = ws + OFF_WKH; Bl = ws + OFF_WKL; Oh = ws + OFF_KH; Ol = ws + OFF_KL; split = true; }
  else             { Ah = ws + OFF_XVH; Al = nullptr;      Bh = ws + OFF_WVH; Bl = nullptr;      Oh = ws + OFF_VT; Ol = nullptr;    split = false; }
  float oscale = (z == 0) ? CEXP : 1.0f;
  int m0 = tile_m * 128, n0 = tile_n * 128;
  int t = threadIdx.x, lane = t & 63, wave = t >> 6;
  int quad = lane >> 4, l15 = lane & 15;
  int wm = (wave >> 1) * 64, wn = (wave & 1) * 64;
  int rl = lane >> 2, cgl = lane & 3;       // staging: 16 rows x 4 chunks/issue
  f32x4 acc[4][4] = {};

  // hoisted staging addresses: issue i covers rows [i*64, i*64+64)
  size_t gA[2], gB[2]; int lb[2];
#pragma unroll
  for (int i = 0; i < 2; ++i) {
    int row = i * 64 + wave * 16 + rl;      // tile-local row 0..127
    int gsw = (cgl ^ ((row >> 1) & 3)) * 8;
    gA[i] = (size_t)(m0 + row) * 1024 + gsw;
    gB[i] = (size_t)(n0 + row) * 1024 + gsw;
    lb[i] = i * 2048 + wave * 512;
  }

  for (int kb = 0; kb < 32; ++kb) {
    int k0 = kb * 32;
    __syncthreads();
#pragma unroll
    for (int i = 0; i < 2; ++i) {
      glds16(Ah + gA[i] + k0, &sAh[lb[i]]);
      if (split) glds16(Al + gA[i] + k0, &sAl[lb[i]]);
      glds16(Bh + gB[i] + k0, &sBh[lb[i]]);
      if (split) glds16(Bl + gB[i] + k0, &sBl[lb[i]]);
    }
    __syncthreads();
    bf16x8 afh[4], afl[4];
#pragma unroll
    for (int mt = 0; mt < 4; ++mt) {
      int ra = wm + mt * 16 + l15;
      afh[mt] = ld8(&sAh[swz32(ra, quad)]);
      if (split) afl[mt] = ld8(&sAl[swz32(ra, quad)]);
    }
#pragma unroll
    for (int nt = 0; nt < 4; ++nt) {
      int rb = wn + nt * 16 + l15;
      bf16x8 bfh = ld8(&sBh[swz32(rb, quad)]);
      bf16x8 bfl;
      if (split) bfl = ld8(&sBl[swz32(rb, quad)]);
#pragma unroll
      for (int mt = 0; mt < 4; ++mt) {
        acc[mt][nt] = __builtin_amdgcn_mfma_f32_16x16x32_bf16(afh[mt], bfh, acc[mt][nt], 0, 0, 0);
        if (split) {
          acc[mt][nt] = __builtin_amdgcn_mfma_f32_16x16x32_bf16(afl[mt], bfh, acc[mt][nt], 0, 0, 0);
          acc[mt][nt] = __builtin_amdgcn_mfma_f32_16x16x32_bf16(afh[mt], bfl, acc[mt][nt], 0, 0, 0);
        }
      }
    }
  }
  // ---- LDS-staged coalesced epilogue (cbuf = 128 rows x 16 chunks, XOR swz) --
  auto epi_round = [&](u16* dst, bool lo_round) {
#pragma unroll
    for (int mt = 0; mt < 4; ++mt)
#pragma unroll
      for (int nt = 0; nt < 4; ++nt)
#pragma unroll
        for (int r = 0; r < 4; ++r) {
          int row = wm + mt * 16 + quad * 4 + r;
          int col = wn + nt * 16 + l15;
          float v = acc[mt][nt][r] * oscale;
          u16 hb = f2b(v);
          u16 val = lo_round ? f2b(v - b2f(hb)) : hb;
          cbuf[row * 128 + (((col >> 3) ^ (row & 15)) * 8) + (col & 7)] = val;
        }
    __syncthreads();
    // store: each thread handles (row, seg) for two 64-row halves
#pragma unroll
    for (int rr = 0; rr < 2; ++rr) {
      int row = rr * 64 + (t >> 2), seg = t & 3;
      int gm = m0 + row, bb = gm >> 11, s = gm & 2047;
      int hh = (n0 >> 6) + (seg >> 1), d0 = (seg & 1) * 32;
      u16* gp = dst + ((size_t)(bb * 16 + hh) * 2048 + s) * 64 + d0;
#pragma unroll
      for (int i = 0; i < 4; ++i) {
        int phys = (seg * 4 + i) ^ (row & 15);
        *(u32x4*)(gp + i * 8) = *(const u32x4*)(&cbuf[row * 128 + phys * 8]);
      }
    }
  };
  __syncthreads();                 // staging reads done; cbuf free
  if (split) {
    epi_round(Oh, false);
    __syncthreads();
    epi_round(Ol, true);
  } else {
    // ---- V: transposed epilogue, writes VT[b,h,d,s] directly ----
#pragma unroll
    for (int mt = 0; mt < 4; ++mt)
#pragma unroll
      for (int nt = 0; nt < 4; ++nt)
#pragma unroll
        for (int r = 0; r < 4; ++r) {
          int row = wm + mt * 16 + quad * 4 + r;       // seq within tile 0..127
          int col = wn + nt * 16 + l15;                // dim within 128 (2 heads)
          cbuf[row * 128 + (((col >> 3) ^ (row & 15)) * 8) + (col & 7)] =
              f2b(acc[mt][nt][r]);
        }
    __syncthreads();
    int col = t >> 1, sh = t & 1;
    int hg = (n0 + col) >> 6, d = (n0 + col) & 63;
    int bb = m0 >> 11, s0 = m0 & 2047;
#pragma unroll
    for (int part = 0; part < 2; ++part) {
      u16 vals[32];
#pragma unroll
      for (int i = 0; i < 32; ++i) {
        int row = part * 64 + sh * 32 + i;
        vals[i] = cbuf[row * 128 + (((col >> 3) ^ (row & 15)) * 8) + (col & 7)];
      }
      u16* gp = Oh + ((size_t)((bb * 16 + hg) * 64 + d)) * 2048 + s0 + part * 64 + sh * 32;
#pragma unroll
      for (int i = 0; i < 4; ++i)
        *(u32x4*)(gp + i * 8) = *(const u32x4*)(&vals[i * 8]);
    }
  }
}

// ---------------- flash attention: 64 Q-rows/block, 64-key tiles -------------
// R14 attn = exact R11 revert (measured 96.0 us; R13's approx-first + shfl
// redistribution regressed to 106.5: doubled LDS reads -> 2x bank conflicts,
// shfl network on the exp->PV critical path). XCD-grouped heads, dead-tile
// skip, exact defer-rescale, setprio, max3 tree, T14 issue-early/write-late.
__global__ __launch_bounds__(256, 4) void attn(const u16* __restrict__ ws,
                                               float* __restrict__ out) {
  __shared__ u16 lkh[64 * 64];
  __shared__ u16 lkl[64 * 64];
  __shared__ u16 lvt[64 * 64];
  __shared__ u16 lp[4][16 * 64];     // per-wave P tile [qrow][key], swz64
  const u16* Qh = ws + OFF_QH; const u16* Ql = ws + OFF_QL;
  const u16* Kh = ws + OFF_KH; const u16* Kl = ws + OFF_KL;
  const u16* Vt = ws + OFF_VT;
  // ---- XCD-grouped decode: xcd owns heads [xcd*4, xcd*4+4) ----
  int id = blockIdx.x;
  int xcd = id & 7, slot = id >> 3;            // slot 0..127
  int hh = xcd * 4 + (slot >> 5);              // 0..31  (b*16+h)
  int q0 = (slot & 31) * 64;
  int b = hh >> 4, h = hh & 15;
  int t = threadIdx.x, lane = t & 63, wave = t >> 6;
  int quad = lane >> 4, l15 = lane & 15;
  size_t hb = (size_t)hh * (2048 * 64);
  bf16x8 onesf;                                  // ones B-frag for row-sum MFMA
#pragma unroll
  for (int j = 0; j < 8; ++j) onesf[j] = __builtin_bit_cast(__bf16, (u16)0x3F80);
  int qrow = q0 + wave * 16 + l15;
  bf16x8 qfh[2], qfl[2];
#pragma unroll
  for (int ks = 0; ks < 2; ++ks) {
    size_t qo = hb + (size_t)qrow * 64 + ks * 32 + quad * 8;
    qfh[ks] = ld8(Qh + qo);
    qfl[ks] = ld8(Ql + qo);
  }
  float mi = -1e30f;                 // running max for qrow=l15 (St domain)
  f32x4 lsum = {};                   // row-sum accumulator (O domain)
  f32x4 o[4] = {};
  int rl = lane >> 3, cgl = lane & 7;            // staging: 8 rows x 8 chunks/issue

  size_t aK[2], aV[2]; int lb[2];
#pragma unroll
  for (int i = 0; i < 2; ++i) {
    int row = wave * 16 + i * 8 + rl;            // tile-local row 0..63
    int cgg = cgl ^ (row & 7);
    aK[i] = hb + (size_t)row * 64 + cgg * 8;     // + kt*4096 in-loop
    aV[i] = hb + (size_t)row * 2048 + cgg * 8;   // + kt*64  in-loop
    lb[i] = (wave * 16 + i * 8) * 64;
  }
  int soF[2][4];
#pragma unroll
  for (int ks = 0; ks < 2; ++ks)
#pragma unroll
    for (int nt = 0; nt < 4; ++nt)
      soF[ks][nt] = swz64(nt * 16 + l15, ks * 4 + quad);
  int soP[4];
  {
    int r7 = l15 & 7;
#pragma unroll
    for (int nt = 0; nt < 4; ++nt) {
      int c = nt * 2 + (quad >> 1);
      soP[nt] = l15 * 64 + ((c ^ r7) * 8) + (quad & 1) * 4;
    }
  }
  int soPa[2];
#pragma unroll
  for (int ks = 0; ks < 2; ++ks) soPa[ks] = swz64(l15, ks * 4 + quad);
  u16* lpw = &lp[wave][0];

  // ---- prologue: stage tile 0 via global_load_lds ----
#pragma unroll
  for (int i = 0; i < 2; ++i) {
    glds16(Kh + aK[i], &lkh[lb[i]]);
    glds16(Kl + aK[i], &lkl[lb[i]]);
    glds16(Vt + aV[i], &lvt[lb[i]]);
  }
  __syncthreads();

  for (int kt = 0; kt < 32; ++kt) {
    // ---- T14 issue-early: prefetch tile kt+1 into registers ----
    u32x4 pk_[2], pl_[2], pv_[2];
    if (kt < 31) {
#pragma unroll
      for (int i = 0; i < 2; ++i) {
        pk_[i] = *(const u32x4*)(Kh + aK[i] + (kt + 1) * 4096);
        pl_[i] = *(const u32x4*)(Kl + aK[i] + (kt + 1) * 4096);
        pv_[i] = *(const u32x4*)(Vt + aV[i] + (kt + 1) * 64);
      }
    }
    // ---- QK^T (swapped): sc[nt] rows=keys nt*16+quad*4+r, col=qrow=l15 ----
    f32x4 sc[4] = {};
    __builtin_amdgcn_s_setprio(1);
#pragma unroll
    for (int nt = 0; nt < 4; ++nt) {
#pragma unroll
      for (int ks = 0; ks < 2; ++ks) {
        bf16x8 kh_ = ld8(&lkh[soF[ks][nt]]);
        bf16x8 kl_ = ld8(&lkl[soF[ks][nt]]);
        sc[nt] = __builtin_amdgcn_mfma_f32_16x16x32_bf16(kh_, qfh[ks], sc[nt], 0, 0, 0);
        sc[nt] = __builtin_amdgcn_mfma_f32_16x16x32_bf16(kl_, qfh[ks], sc[nt], 0, 0, 0);
        sc[nt] = __builtin_amdgcn_mfma_f32_16x16x32_bf16(kh_, qfl[ks], sc[nt], 0, 0, 0);
      }
    }
    __builtin_amdgcn_s_setprio(0);
    // ---- online softmax: max3-friendly tree + 2 shfl ----
    float t0 = fmaxf(fmaxf(sc[0][0], sc[0][1]), sc[0][2]);
    float t1 = fmaxf(fmaxf(sc[0][3], sc[1][0]), sc[1][1]);
    float t2 = fmaxf(fmaxf(sc[1][2], sc[1][3]), sc[2][0]);
    float t3 = fmaxf(fmaxf(sc[2][1], sc[2][2]), sc[2][3]);
    float t4 = fmaxf(fmaxf(sc[3][0], sc[3][1]), sc[3][2]);
    float mx = fmaxf(fmaxf(fmaxf(t0, t1), fmaxf(t2, t3)), fmaxf(t4, sc[3][3]));
    mx = fmaxf(mx, __shfl_xor(mx, 16));
    mx = fmaxf(mx, __shfl_xor(mx, 32));
    float mi_old = mi;
    // ---- dead-tile test: any row within 28 exp2-units of its running max?
    unsigned long long live = __ballot(mx > mi_old - 28.0f);
    float mn = fmaxf(mi_old, mx);
    mi = mn;
    if (live) {
      unsigned long long grew = __ballot(mx > mi_old);   // wave-uniform
      // ---- P = exp2(sc - mn), packed ds_write_b64 into lp[qrow][key] ----
#pragma unroll
      for (int nt = 0; nt < 4; ++nt) {
        unsigned u01 = pk2(ex2(sc[nt][0] - mn), ex2(sc[nt][1] - mn));
        unsigned u23 = pk2(ex2(sc[nt][2] - mn), ex2(sc[nt][3] - mn));
        *(u32x2*)(&lpw[soP[nt]]) = u32x2{u01, u23};
      }
      // ---- rescale only if some row's max grew (else alpha==1 exactly) ----
      if (grew) {
        float alpha_s = ex2(mi_old - mn);
        float av[4];
#pragma unroll
        for (int r = 0; r < 4; ++r) av[r] = __shfl(alpha_s, quad * 4 + r);
#pragma unroll
        for (int r = 0; r < 4; ++r) {
          lsum[r] *= av[r];
          o[0][r] *= av[r]; o[1][r] *= av[r]; o[2][r] *= av[r]; o[3][r] *= av[r];
        }
      }
      // wave-private LDS write->read: drain DS queue (in-order per wave)
      asm volatile("s_waitcnt lgkmcnt(0)" ::: "memory");
      // ---- P @ V (+ ones-B MFMA accumulates the row-sum l) ----
      bf16x8 pa[2];
#pragma unroll
      for (int ks = 0; ks < 2; ++ks) pa[ks] = ld8(&lpw[soPa[ks]]);
      __builtin_amdgcn_s_setprio(1);
      lsum = __builtin_amdgcn_mfma_f32_16x16x32_bf16(pa[0], onesf, lsum, 0, 0, 0);
      lsum = __builtin_amdgcn_mfma_f32_16x16x32_bf16(pa[1], onesf, lsum, 0, 0, 0);
#pragma unroll
      for (int nt = 0; nt < 4; ++nt)
#pragma unroll
        for (int ks = 0; ks < 2; ++ks) {
          bf16x8 bv = ld8(&lvt[soF[ks][nt]]);
          o[nt] = __builtin_amdgcn_mfma_f32_16x16x32_bf16(pa[ks], bv, o[nt], 0, 0, 0);
        }
      __builtin_amdgcn_s_setprio(0);
    }
    // ---- write-late: all waves done reading tile kt; commit tile kt+1 ----
    __syncthreads();
    if (kt < 31) {
#pragma unroll
      for (int i = 0; i < 2; ++i) {
        *(u32x4*)(&lkh[lb[i] + lane * 8]) = pk_[i];
        *(u32x4*)(&lkl[lb[i] + lane * 8]) = pl_[i];
        *(u32x4*)(&lvt[lb[i] + lane * 8]) = pv_[i];
      }
    }
    __syncthreads();
  }
  // epilogue: out[b, s, h*64+d]
  float inv[4];
#pragma unroll
  for (int r = 0; r < 4; ++r) inv[r] = 1.0f / lsum[r];
#pragma unroll
  for (int nt = 0; nt < 4; ++nt)
#pragma unroll
    for (int r = 0; r < 4; ++r) {
      int srow = q0 + wave * 16 + quad * 4 + r;
      int d = nt * 16 + l15;
      out[(size_t)(b * 2048 + srow) * 1024 + h * 64 + d] = o[nt][r] * inv[r];
    }
}

extern "C" void kernel_launch(void* const* d_in, const int* in_sizes, int n_in,
                              void* d_out, int out_size, void* d_ws, size_t ws_size,
                              hipStream_t stream) {
  const float* q  = (const float*)d_in[0];
  const float* k  = (const float*)d_in[1];
  const float* v  = (const float*)d_in[2];
  const float* Wq = (const float*)d_in[3];
  const float* Wk = (const float*)d_in[4];
  const float* Wv = (const float*)d_in[5];
  u16* ws = (u16*)d_ws;
  float* out = (float*)d_out;

  convert_all<<<15360, 256, 0, stream>>>(q, k, v, Wq, Wk, Wv, ws);
  gemm_qkv<<<768, 256, 0, stream>>>(ws);
  attn<<<1024, 256, 0, stream>>>(ws, out);
}

// Round 8
// 266.870 us; speedup vs baseline: 1.0428x; 1.0291x over previous
//
#include <hip/hip_runtime.h>
#include <cstdint>
#include <cstddef>

typedef unsigned short u16;
typedef __bf16 bf16x8 __attribute__((ext_vector_type(8)));
typedef float f32x4 __attribute__((ext_vector_type(4)));
typedef unsigned int u32x4 __attribute__((ext_vector_type(4)));
typedef unsigned int u32x2 __attribute__((ext_vector_type(2)));
typedef u16 u16x4 __attribute__((ext_vector_type(4)));

typedef __attribute__((address_space(3))) void lds_void;
typedef __attribute__((address_space(1))) void glb_void;

constexpr float CEXP = 92.33248261689366f;   // 64 * log2(e): folded into Q

// ---------------- workspace layout (u16 element offsets) ----------------
constexpr size_t XSZ = 4096ull * 1024ull;   // one [4096,1024] bf16 array
constexpr size_t WSZ = 1024ull * 1024ull;   // one [1024,1024] bf16 array
constexpr size_t OFF_XQH = 0;
constexpr size_t OFF_XQL = OFF_XQH + XSZ;
constexpr size_t OFF_XKH = OFF_XQL + XSZ;
constexpr size_t OFF_XKL = OFF_XKH + XSZ;
constexpr size_t OFF_XVH = OFF_XKL + XSZ;
constexpr size_t OFF_XVL = OFF_XVH + XSZ;   // UNUSED (kept for layout stability)
constexpr size_t OFF_WQH = OFF_XVL + XSZ;
constexpr size_t OFF_WQL = OFF_WQH + WSZ;
constexpr size_t OFF_WKH = OFF_WQL + WSZ;
constexpr size_t OFF_WKL = OFF_WKH + WSZ;
constexpr size_t OFF_WVH = OFF_WKL + WSZ;
constexpr size_t OFF_WVL = OFF_WVH + WSZ;   // UNUSED
constexpr size_t OFF_QH  = OFF_WVL + WSZ;   // [B,H,S,64]  (pre-scaled by CEXP)
constexpr size_t OFF_QL  = OFF_QH + XSZ;
constexpr size_t OFF_KH  = OFF_QL + XSZ;
constexpr size_t OFF_KL  = OFF_KH + XSZ;
constexpr size_t OFF_VH  = OFF_KL + XSZ;    // UNUSED (V-GEMM writes VT directly)
constexpr size_t OFF_VT  = OFF_VH + XSZ;    // [B,H,64,S]

// ---------------- helpers ----------------
__device__ __forceinline__ u16 f2b(float f) {           // fp32 -> bf16 RNE
  unsigned u = __builtin_bit_cast(unsigned, f);
  return (u16)((u + 0x7FFFu + ((u >> 16) & 1u)) >> 16);
}
__device__ __forceinline__ float b2f(u16 h) {
  return __builtin_bit_cast(float, ((unsigned)h) << 16);
}
__device__ __forceinline__ bf16x8 ld8(const u16* p) {   // 16B frag load
  return __builtin_bit_cast(bf16x8, *(const u32x4*)p);
}
__device__ __forceinline__ unsigned pk2(float a, float b) {  // pack 2 bf16 (RNE)
#if __has_builtin(__builtin_amdgcn_cvt_pk_bf16_f32)
  auto v = __builtin_amdgcn_cvt_pk_bf16_f32(a, b);
  return __builtin_bit_cast(unsigned, v);
#else
  return (unsigned)f2b(a) | ((unsigned)f2b(b) << 16);
#endif
}
__device__ __forceinline__ float ex2(float x) {         // raw v_exp_f32
#if __has_builtin(__builtin_amdgcn_exp2f)
  return __builtin_amdgcn_exp2f(x);
#else
  return exp2f(x);
#endif
}
__device__ __forceinline__ void glds16(const u16* g, u16* l) { // 16B global->LDS
  __builtin_amdgcn_global_load_lds((const glb_void*)g, (lds_void*)l, 16, 0, 0);
}
// swizzled LDS offset for a [rows][32 u16] tile: chunk = 8 u16 (16B)
__device__ __forceinline__ int swz32(int row, int cg) {
  return row * 32 + ((cg ^ ((row >> 1) & 3)) * 8);
}
// swizzled LDS offset for a [rows][64 u16] tile: chunk = 8 u16 (16B)
__device__ __forceinline__ int swz64(int row, int cg) {
  return row * 64 + ((cg ^ (row & 7)) * 8);
}

// ---------------- fused converts: x (hi/lo) + W^T (hi/lo) ----------------
// R15: x path does 8 floats/thread (32B read, one 16B hi store + one 16B lo
// store) -> grid 15360 -> 9216 blocks. Probes whether convert was
// block-overhead-bound.
__global__ __launch_bounds__(256) void convert_all(const float* __restrict__ q,
                                                   const float* __restrict__ k,
                                                   const float* __restrict__ v,
                                                   const float* __restrict__ Wq,
                                                   const float* __restrict__ Wk,
                                                   const float* __restrict__ Wv,
                                                   u16* __restrict__ ws) {
  __shared__ float tile[32][33];
  int id = blockIdx.x;
  int t = threadIdx.x;
  if (id < 6144) {                        // ---- x path: 2048 blocks per z ----
    int z = id >> 11, blk = id & 2047;
    const float* in = (z == 0) ? q : (z == 1) ? k : v;
    u16* hi = ws + ((z == 0) ? OFF_XQH : (z == 1) ? OFF_XKH : OFF_XVH);
    u16* lo = ws + ((z == 0) ? OFF_XQL : (z == 1) ? OFF_XKL : OFF_XVL);
    size_t i = ((size_t)blk * 256u + t) * 8u;
    float4 v0 = *(const float4*)(in + i);
    float4 v1 = *(const float4*)(in + i + 4);
    float a[8] = {v0.x, v0.y, v0.z, v0.w, v1.x, v1.y, v1.z, v1.w};
    u16 hv[8], lv[8];
#pragma unroll
    for (int j = 0; j < 8; ++j) {
      u16 hb = f2b(a[j]);
      hv[j] = hb;
      lv[j] = f2b(a[j] - b2f(hb));
    }
    *(u32x4*)(hi + i) = *(const u32x4*)hv;
    if (z != 2) *(u32x4*)(lo + i) = *(const u32x4*)lv;
  } else {                                // ---- W path: 1024 blocks per z ----
    int r0 = id - 6144;
    int z = r0 >> 10, rem = r0 & 1023;
    const float* W = (z == 0) ? Wq : (z == 1) ? Wk : Wv;
    u16* hiT = ws + ((z == 0) ? OFF_WQH : (z == 1) ? OFF_WKH : OFF_WVH);
    u16* loT = ws + ((z == 0) ? OFF_WQL : (z == 1) ? OFF_WKL : OFF_WVL);
    int n0 = (rem & 31) * 32, k0 = (rem >> 5) * 32;
    int r = t >> 3, c0 = (t & 7) * 4;
    float4 vv = *(const float4*)(W + (size_t)(k0 + r) * 1024 + n0 + c0);
    tile[r][c0] = vv.x; tile[r][c0 + 1] = vv.y; tile[r][c0 + 2] = vv.z; tile[r][c0 + 3] = vv.w;
    __syncthreads();
    u16x4 hv, lv;
#pragma unroll
    for (int j = 0; j < 4; ++j) {
      float x = tile[c0 + j][r];          // = W[k0+c0+j][n0+r]
      u16 hb = f2b(x);
      hv[j] = hb;
      lv[j] = f2b(x - b2f(hb));
    }
    size_t o = (size_t)(n0 + r) * 1024 + k0 + c0;
    *(u16x4*)(hiT + o) = hv;
    if (z != 2) *(u16x4*)(loT + o) = lv;
  }
}

// ---------------- QKV projection GEMM, 128x128 tile, 4 waves -----------------
// (unchanged from R14; tile-size proven non-lever, awaiting visibility)
__global__ __launch_bounds__(256, 3) void gemm_qkv(u16* __restrict__ ws) {
  __shared__ u16 smem[16384];          // 32 KB: staging arrays / cbuf view
  u16* sAh = smem;                     // [128*32] each (8 KB)
  u16* sAl = smem + 4096;
  u16* sBh = smem + 8192;
  u16* sBl = smem + 12288;
  u16* cbuf = smem;                    // 128x128 u16 epilogue view (32 KB)

  int id = blockIdx.x;
  int xcd = id & 7, seq = id >> 3;          // seq 0..95
  int pair = (seq >> 3) * 8 + xcd;          // 0..95, z-balanced per XCD
  int tile_n = seq & 7;
  int z = pair >> 5;                        // 0..2
  int tile_m = pair & 31;

  const u16 *Ah, *Al, *Bh, *Bl; u16 *Oh, *Ol; bool split;
  if (z == 0)      { Ah = ws + OFF_XQH; Al = ws + OFF_XQL; Bh = ws + OFF_WQH; Bl = ws + OFF_WQL; Oh = ws + OFF_QH; Ol = ws + OFF_QL; split = true; }
  else if (z == 1) { Ah = ws + OFF_XKH; Al = ws + OFF_XKL; Bh = ws + OFF_WKH; Bl = ws + OFF_WKL; Oh = ws + OFF_KH; Ol = ws + OFF_KL; split = true; }
  else             { Ah = ws + OFF_XVH; Al = nullptr;      Bh = ws + OFF_WVH; Bl = nullptr;      Oh = ws + OFF_VT; Ol = nullptr;    split = false; }
  float oscale = (z == 0) ? CEXP : 1.0f;
  int m0 = tile_m * 128, n0 = tile_n * 128;
  int t = threadIdx.x, lane = t & 63, wave = t >> 6;
  int quad = lane >> 4, l15 = lane & 15;
  int wm = (wave >> 1) * 64, wn = (wave & 1) * 64;
  int rl = lane >> 2, cgl = lane & 3;       // staging: 16 rows x 4 chunks/issue
  f32x4 acc[4][4] = {};

  size_t gA[2], gB[2]; int lb[2];
#pragma unroll
  for (int i = 0; i < 2; ++i) {
    int row = i * 64 + wave * 16 + rl;      // tile-local row 0..127
    int gsw = (cgl ^ ((row >> 1) & 3)) * 8;
    gA[i] = (size_t)(m0 + row) * 1024 + gsw;
    gB[i] = (size_t)(n0 + row) * 1024 + gsw;
    lb[i] = i * 2048 + wave * 512;
  }

  for (int kb = 0; kb < 32; ++kb) {
    int k0 = kb * 32;
    __syncthreads();
#pragma unroll
    for (int i = 0; i < 2; ++i) {
      glds16(Ah + gA[i] + k0, &sAh[lb[i]]);
      if (split) glds16(Al + gA[i] + k0, &sAl[lb[i]]);
      glds16(Bh + gB[i] + k0, &sBh[lb[i]]);
      if (split) glds16(Bl + gB[i] + k0, &sBl[lb[i]]);
    }
    __syncthreads();
    bf16x8 afh[4], afl[4];
#pragma unroll
    for (int mt = 0; mt < 4; ++mt) {
      int ra = wm + mt * 16 + l15;
      afh[mt] = ld8(&sAh[swz32(ra, quad)]);
      if (split) afl[mt] = ld8(&sAl[swz32(ra, quad)]);
    }
#pragma unroll
    for (int nt = 0; nt < 4; ++nt) {
      int rb = wn + nt * 16 + l15;
      bf16x8 bfh = ld8(&sBh[swz32(rb, quad)]);
      bf16x8 bfl;
      if (split) bfl = ld8(&sBl[swz32(rb, quad)]);
#pragma unroll
      for (int mt = 0; mt < 4; ++mt) {
        acc[mt][nt] = __builtin_amdgcn_mfma_f32_16x16x32_bf16(afh[mt], bfh, acc[mt][nt], 0, 0, 0);
        if (split) {
          acc[mt][nt] = __builtin_amdgcn_mfma_f32_16x16x32_bf16(afl[mt], bfh, acc[mt][nt], 0, 0, 0);
          acc[mt][nt] = __builtin_amdgcn_mfma_f32_16x16x32_bf16(afh[mt], bfl, acc[mt][nt], 0, 0, 0);
        }
      }
    }
  }
  auto epi_round = [&](u16* dst, bool lo_round) {
#pragma unroll
    for (int mt = 0; mt < 4; ++mt)
#pragma unroll
      for (int nt = 0; nt < 4; ++nt)
#pragma unroll
        for (int r = 0; r < 4; ++r) {
          int row = wm + mt * 16 + quad * 4 + r;
          int col = wn + nt * 16 + l15;
          float v = acc[mt][nt][r] * oscale;
          u16 hb = f2b(v);
          u16 val = lo_round ? f2b(v - b2f(hb)) : hb;
          cbuf[row * 128 + (((col >> 3) ^ (row & 15)) * 8) + (col & 7)] = val;
        }
    __syncthreads();
#pragma unroll
    for (int rr = 0; rr < 2; ++rr) {
      int row = rr * 64 + (t >> 2), seg = t & 3;
      int gm = m0 + row, bb = gm >> 11, s = gm & 2047;
      int hh = (n0 >> 6) + (seg >> 1), d0 = (seg & 1) * 32;
      u16* gp = dst + ((size_t)(bb * 16 + hh) * 2048 + s) * 64 + d0;
#pragma unroll
      for (int i = 0; i < 4; ++i) {
        int phys = (seg * 4 + i) ^ (row & 15);
        *(u32x4*)(gp + i * 8) = *(const u32x4*)(&cbuf[row * 128 + phys * 8]);
      }
    }
  };
  __syncthreads();                 // staging reads done; cbuf free
  if (split) {
    epi_round(Oh, false);
    __syncthreads();
    epi_round(Ol, true);
  } else {
    // ---- V: transposed epilogue, writes VT[b,h,d,s] directly ----
#pragma unroll
    for (int mt = 0; mt < 4; ++mt)
#pragma unroll
      for (int nt = 0; nt < 4; ++nt)
#pragma unroll
        for (int r = 0; r < 4; ++r) {
          int row = wm + mt * 16 + quad * 4 + r;       // seq within tile 0..127
          int col = wn + nt * 16 + l15;                // dim within 128 (2 heads)
          cbuf[row * 128 + (((col >> 3) ^ (row & 15)) * 8) + (col & 7)] =
              f2b(acc[mt][nt][r]);
        }
    __syncthreads();
    int col = t >> 1, sh = t & 1;
    int hg = (n0 + col) >> 6, d = (n0 + col) & 63;
    int bb = m0 >> 11, s0 = m0 & 2047;
#pragma unroll
    for (int part = 0; part < 2; ++part) {
      u16 vals[32];
#pragma unroll
      for (int i = 0; i < 32; ++i) {
        int row = part * 64 + sh * 32 + i;
        vals[i] = cbuf[row * 128 + (((col >> 3) ^ (row & 15)) * 8) + (col & 7)];
      }
      u16* gp = Oh + ((size_t)((bb * 16 + hg) * 64 + d)) * 2048 + s0 + part * 64 + sh * 32;
#pragma unroll
      for (int i = 0; i < 4; ++i)
        *(u32x4*)(gp + i * 8) = *(const u32x4*)(&vals[i * 8]);
    }
  }
}

// ---------------- flash attention: 64 Q-rows/block, 64-key tiles -------------
// R15 = R11 + SWAPPED PV: the pa regs (P[keys 32ks+8q+j][qrow=l15]) are a
// valid B-frag (n=qrow) as well as an A-frag, so o^T = mfma(bv, pa) and
// lsum = mfma(ones, pa) are FREE. O/lsum/mi/alpha now all live in the
// lane=qrow=l15 domain: the 4 alpha-broadcast shuffles are gone and the
// epilogue stores contiguous f32x4. (R13's regression was the shfl
// redistribution + frag re-reads, both absent here.)
__global__ __launch_bounds__(256, 4) void attn(const u16* __restrict__ ws,
                                               float* __restrict__ out) {
  __shared__ u16 lkh[64 * 64];
  __shared__ u16 lkl[64 * 64];
  __shared__ u16 lvt[64 * 64];
  __shared__ u16 lp[4][16 * 64];     // per-wave P tile [qrow][key], swz64
  const u16* Qh = ws + OFF_QH; const u16* Ql = ws + OFF_QL;
  const u16* Kh = ws + OFF_KH; const u16* Kl = ws + OFF_KL;
  const u16* Vt = ws + OFF_VT;
  // ---- XCD-grouped decode: xcd owns heads [xcd*4, xcd*4+4) ----
  int id = blockIdx.x;
  int xcd = id & 7, slot = id >> 3;            // slot 0..127
  int hh = xcd * 4 + (slot >> 5);              // 0..31  (b*16+h)
  int q0 = (slot & 31) * 64;
  int b = hh >> 4, h = hh & 15;
  int t = threadIdx.x, lane = t & 63, wave = t >> 6;
  int quad = lane >> 4, l15 = lane & 15;
  size_t hb = (size_t)hh * (2048 * 64);
  bf16x8 onesf;                                  // ones A-frag for row-sum MFMA
#pragma unroll
  for (int j = 0; j < 8; ++j) onesf[j] = __builtin_bit_cast(__bf16, (u16)0x3F80);
  int qrow = q0 + wave * 16 + l15;
  bf16x8 qfh[2], qfl[2];
#pragma unroll
  for (int ks = 0; ks < 2; ++ks) {
    size_t qo = hb + (size_t)qrow * 64 + ks * 32 + quad * 8;
    qfh[ks] = ld8(Qh + qo);
    qfl[ks] = ld8(Ql + qo);
  }
  float mi = -1e30f;                 // running max for qrow=l15
  f32x4 lsum = {};                   // row-sum accumulator (all 4 regs equal)
  f32x4 o[4] = {};                   // o^T: col=l15=qrow, row=d
  int rl = lane >> 3, cgl = lane & 7;            // staging: 8 rows x 8 chunks/issue

  size_t aK[2], aV[2]; int lb[2];
#pragma unroll
  for (int i = 0; i < 2; ++i) {
    int row = wave * 16 + i * 8 + rl;            // tile-local row 0..63
    int cgg = cgl ^ (row & 7);
    aK[i] = hb + (size_t)row * 64 + cgg * 8;     // + kt*4096 in-loop
    aV[i] = hb + (size_t)row * 2048 + cgg * 8;   // + kt*64  in-loop
    lb[i] = (wave * 16 + i * 8) * 64;
  }
  int soF[2][4];
#pragma unroll
  for (int ks = 0; ks < 2; ++ks)
#pragma unroll
    for (int nt = 0; nt < 4; ++nt)
      soF[ks][nt] = swz64(nt * 16 + l15, ks * 4 + quad);
  int soP[4];
  {
    int r7 = l15 & 7;
#pragma unroll
    for (int nt = 0; nt < 4; ++nt) {
      int c = nt * 2 + (quad >> 1);
      soP[nt] = l15 * 64 + ((c ^ r7) * 8) + (quad & 1) * 4;
    }
  }
  int soPa[2];
#pragma unroll
  for (int ks = 0; ks < 2; ++ks) soPa[ks] = swz64(l15, ks * 4 + quad);
  u16* lpw = &lp[wave][0];

  // ---- prologue: stage tile 0 via global_load_lds ----
#pragma unroll
  for (int i = 0; i < 2; ++i) {
    glds16(Kh + aK[i], &lkh[lb[i]]);
    glds16(Kl + aK[i], &lkl[lb[i]]);
    glds16(Vt + aV[i], &lvt[lb[i]]);
  }
  __syncthreads();

  for (int kt = 0; kt < 32; ++kt) {
    // ---- T14 issue-early: prefetch tile kt+1 into registers ----
    u32x4 pk_[2], pl_[2], pv_[2];
    if (kt < 31) {
#pragma unroll
      for (int i = 0; i < 2; ++i) {
        pk_[i] = *(const u32x4*)(Kh + aK[i] + (kt + 1) * 4096);
        pl_[i] = *(const u32x4*)(Kl + aK[i] + (kt + 1) * 4096);
        pv_[i] = *(const u32x4*)(Vt + aV[i] + (kt + 1) * 64);
      }
    }
    // ---- QK^T (swapped): sc[nt] rows=keys nt*16+quad*4+r, col=qrow=l15 ----
    f32x4 sc[4] = {};
    __builtin_amdgcn_s_setprio(1);
#pragma unroll
    for (int nt = 0; nt < 4; ++nt) {
#pragma unroll
      for (int ks = 0; ks < 2; ++ks) {
        bf16x8 kh_ = ld8(&lkh[soF[ks][nt]]);
        bf16x8 kl_ = ld8(&lkl[soF[ks][nt]]);
        sc[nt] = __builtin_amdgcn_mfma_f32_16x16x32_bf16(kh_, qfh[ks], sc[nt], 0, 0, 0);
        sc[nt] = __builtin_amdgcn_mfma_f32_16x16x32_bf16(kl_, qfh[ks], sc[nt], 0, 0, 0);
        sc[nt] = __builtin_amdgcn_mfma_f32_16x16x32_bf16(kh_, qfl[ks], sc[nt], 0, 0, 0);
      }
    }
    __builtin_amdgcn_s_setprio(0);
    // ---- online softmax: max3-friendly tree + 2 shfl ----
    float t0 = fmaxf(fmaxf(sc[0][0], sc[0][1]), sc[0][2]);
    float t1 = fmaxf(fmaxf(sc[0][3], sc[1][0]), sc[1][1]);
    float t2 = fmaxf(fmaxf(sc[1][2], sc[1][3]), sc[2][0]);
    float t3 = fmaxf(fmaxf(sc[2][1], sc[2][2]), sc[2][3]);
    float t4 = fmaxf(fmaxf(sc[3][0], sc[3][1]), sc[3][2]);
    float mx = fmaxf(fmaxf(fmaxf(t0, t1), fmaxf(t2, t3)), fmaxf(t4, sc[3][3]));
    mx = fmaxf(mx, __shfl_xor(mx, 16));
    mx = fmaxf(mx, __shfl_xor(mx, 32));
    float mi_old = mi;
    // ---- dead-tile test: any row within 28 exp2-units of its running max?
    unsigned long long live = __ballot(mx > mi_old - 28.0f);
    float mn = fmaxf(mi_old, mx);
    mi = mn;
    if (live) {
      unsigned long long grew = __ballot(mx > mi_old);   // wave-uniform
      // ---- P = exp2(sc - mn), packed ds_write_b64 into lp[qrow][key] ----
#pragma unroll
      for (int nt = 0; nt < 4; ++nt) {
        unsigned u01 = pk2(ex2(sc[nt][0] - mn), ex2(sc[nt][1] - mn));
        unsigned u23 = pk2(ex2(sc[nt][2] - mn), ex2(sc[nt][3] - mn));
        *(u32x2*)(&lpw[soP[nt]]) = u32x2{u01, u23};
      }
      // ---- rescale (alpha per-lane: qrow=l15 domain; no broadcast) ----
      if (grew) {
        float a = ex2(mi_old - mn);
#pragma unroll
        for (int r = 0; r < 4; ++r) {
          lsum[r] *= a;
          o[0][r] *= a; o[1][r] *= a; o[2][r] *= a; o[3][r] *= a;
        }
      }
      // wave-private LDS write->read: drain DS queue (in-order per wave)
      asm volatile("s_waitcnt lgkmcnt(0)" ::: "memory");
      // ---- swapped PV: o^T += V-frag (A) x P (B); lsum via ones-A ----
      bf16x8 pa[2];
#pragma unroll
      for (int ks = 0; ks < 2; ++ks) pa[ks] = ld8(&lpw[soPa[ks]]);
      __builtin_amdgcn_s_setprio(1);
      lsum = __builtin_amdgcn_mfma_f32_16x16x32_bf16(onesf, pa[0], lsum, 0, 0, 0);
      lsum = __builtin_amdgcn_mfma_f32_16x16x32_bf16(onesf, pa[1], lsum, 0, 0, 0);
#pragma unroll
      for (int nt = 0; nt < 4; ++nt)
#pragma unroll
        for (int ks = 0; ks < 2; ++ks) {
          bf16x8 bv = ld8(&lvt[soF[ks][nt]]);
          o[nt] = __builtin_amdgcn_mfma_f32_16x16x32_bf16(bv, pa[ks], o[nt], 0, 0, 0);
        }
      __builtin_amdgcn_s_setprio(0);
    }
    // ---- write-late: all waves done reading tile kt; commit tile kt+1 ----
    __syncthreads();
    if (kt < 31) {
#pragma unroll
      for (int i = 0; i < 2; ++i) {
        *(u32x4*)(&lkh[lb[i] + lane * 8]) = pk_[i];
        *(u32x4*)(&lkl[lb[i] + lane * 8]) = pl_[i];
        *(u32x4*)(&lvt[lb[i] + lane * 8]) = pv_[i];
      }
    }
    __syncthreads();
  }
  // epilogue: o^T -> out[b, qrow, h*64 + d], contiguous f32x4 per (nt,quad)
  float inv = 1.0f / lsum[0];
  float* op = out + (size_t)(b * 2048 + q0 + wave * 16 + l15) * 1024 + h * 64;
#pragma unroll
  for (int nt = 0; nt < 4; ++nt) {
    f32x4 w;
#pragma unroll
    for (int r = 0; r < 4; ++r) w[r] = o[nt][r] * inv;
    *(f32x4*)(op + nt * 16 + quad * 4) = w;
  }
}

extern "C" void kernel_launch(void* const* d_in, const int* in_sizes, int n_in,
                              void* d_out, int out_size, void* d_ws, size_t ws_size,
                              hipStream_t stream) {
  const float* q  = (const float*)d_in[0];
  const float* k  = (const float*)d_in[1];
  const float* v  = (const float*)d_in[2];
  const float* Wq = (const float*)d_in[3];
  const float* Wk = (const float*)d_in[4];
  const float* Wv = (const float*)d_in[5];
  u16* ws = (u16*)d_ws;
  float* out = (float*)d_out;

  convert_all<<<9216, 256, 0, stream>>>(q, k, v, Wq, Wk, Wv, ws);
  gemm_qkv<<<768, 256, 0, stream>>>(ws);
  attn<<<1024, 256, 0, stream>>>(ws, out);
}